// Round 15
// baseline (27.998 us; speedup 1.0000x reference)
//
#include <hip/hip_runtime.h>

#define RS 7
#define SR 2
#define PD 10
#define CH (PD * RS * RS)   // 490
#define SCALE (1.0f / 16.0f)
#define HH 100
#define WW 100
#define NPLANE (HH * WW)    // 10000
#define SLOTS 2532          // 16B slots per buffer (data 2500 + pad; stride-60 tail)
#define BUFF (SLOTS * 4)    // 10128 floats = 40512 B
#define TPB 512
#define NBLK 512            // 2 blocks per CU
#define MAXN 4096
#define RSL 4               // register param slots per thread (covers cnt <= 2048)

// async global->LDS, 16B per lane; LDS dest is WAVE-UNIFORM base (+lane*16 by HW)
__device__ __forceinline__ void gll16(const void* g, void* l) {
    __builtin_amdgcn_global_load_lds(
        (const __attribute__((address_space(1))) void*)g,
        (__attribute__((address_space(3))) void*)l, 16, 0, 0);
}

__device__ __forceinline__ void waitv(int allowed) {
    switch (allowed) {
        case 0: asm volatile("s_waitcnt vmcnt(0)" ::: "memory"); break;
        case 1: asm volatile("s_waitcnt vmcnt(1)" ::: "memory"); break;
        case 2: asm volatile("s_waitcnt vmcnt(2)" ::: "memory"); break;
        case 3: asm volatile("s_waitcnt vmcnt(3)" ::: "memory"); break;
        case 4: asm volatile("s_waitcnt vmcnt(4)" ::: "memory"); break;
        case 5: asm volatile("s_waitcnt vmcnt(5)" ::: "memory"); break;
        default: asm volatile("s_waitcnt vmcnt(0)" ::: "memory"); break;
    }
}

__device__ __forceinline__ float psroi_sample_f32(const float* __restrict__ plane,
                                                  float sw, float sh, float bw, float bh,
                                                  int ph, int pw)
{
    float acc = 0.0f;
    #pragma unroll
    for (int iy = 0; iy < SR; ++iy) {
        float y  = sh + ((float)ph + ((float)iy + 0.5f) * (1.0f / SR)) * bh;
        bool  vy = (y >= -1.0f) && (y <= (float)HH);
        float yy = fmaxf(y, 0.0f);
        int   y0 = min((int)floorf(yy), HH - 1);
        int   y1 = min(y0 + 1, HH - 1);
        float yc = (y0 >= HH - 1) ? (float)y0 : yy;
        float ly = yc - (float)y0;
        float hy = 1.0f - ly;
        #pragma unroll
        for (int ix = 0; ix < SR; ++ix) {
            float x  = sw + ((float)pw + ((float)ix + 0.5f) * (1.0f / SR)) * bw;
            bool  vx = (x >= -1.0f) && (x <= (float)WW);
            float xx = fmaxf(x, 0.0f);
            int   x0 = min((int)floorf(xx), WW - 1);
            int   x1 = min(x0 + 1, WW - 1);
            float xc = (x0 >= WW - 1) ? (float)x0 : xx;
            float lx = xc - (float)x0;
            float hx = 1.0f - lx;
            float v00 = plane[y0 * WW + x0];
            float v01 = plane[y0 * WW + x1];
            float v10 = plane[y1 * WW + x0];
            float v11 = plane[y1 * WW + x1];
            float v = hy * (hx * v00 + lx * v01) + ly * (hx * v10 + lx * v11);
            if (vy && vx) acc += v;
        }
    }
    return acc * (1.0f / (SR * SR));
}

// persistent dbuf pipeline: 512 blocks (2/CU) x 512 thr, 3-4 tiles/block,
// ROI params in registers, planes DMA'd to LDS.
__global__ __launch_bounds__(TPB, 4) void psroi_pipe2_kernel(
    const float* __restrict__ feat, const float* __restrict__ rois,
    float* __restrict__ out, int N)
{
    __shared__ __align__(16) float buf0[BUFF];    // 40.5 KB
    __shared__ __align__(16) float buf1[BUFF];    // 40.5 KB
    __shared__ int lcnt;

    int tid  = threadIdx.x;
    int wid  = tid >> 6;
    int lane = tid & 63;
    int bid  = blockIdx.x;
    int xcd  = bid & 7;                    // heuristic XCD id (perf-only)
    int idx  = bid >> 3;                   // 0..63 within XCD
    int b    = xcd >> 1;                   // batch
    int cinbase = (xcd & 1) * 245;         // half-slice of cins
    int ntile = (245 - 1 - idx) / 64 + 1;  // 4 (idx<53) or 3

    if (tid == 0) lcnt = 0;
    __syncthreads();

    // ---- 1) scan rois -> compact index list in buf0 (temp) ----
    int* list = (int*)buf0;
    for (int k0 = 0; k0 < N; k0 += TPB) {
        int k = k0 + tid;
        bool m = (k < N) && ((int)rois[(size_t)k * 5] == b);
        unsigned long long msk = __ballot(m);
        if (m) {
            int rank   = __popcll(msk & ((1ull << lane) - 1ull));
            int leader = __ffsll((long long)msk) - 1;
            int pos = 0;
            if (lane == leader) pos = atomicAdd(&lcnt, (int)__popcll(msk));
            pos = __shfl(pos, leader) + rank;
            list[pos] = k;
        }
    }
    __syncthreads();
    int cnt = lcnt;

    // ---- 2) load my RSL ROI params into REGISTERS ----
    float psw[RSL], psh[RSL], pbw[RSL], pbh[RSL];
    int   pn[RSL];
    #pragma unroll
    for (int s = 0; s < RSL; ++s) {
        int i = tid + s * TPB;
        pn[s] = -1;
        psw[s] = psh[s] = pbw[s] = pbh[s] = 0.0f;
        if (i < cnt) {
            int n = list[i];
            pn[s] = n;
            const float* rp = rois + (size_t)n * 5;
            float sw = rp[1] * SCALE - 0.5f;
            float sh = rp[2] * SCALE - 0.5f;
            psw[s] = sw;
            psh[s] = sh;
            pbw[s] = (rp[3] * SCALE - 0.5f - sw) * (1.0f / RS);
            pbh[s] = (rp[4] * SCALE - 0.5f - sh) * (1.0f / RS);
        }
    }
    __syncthreads();   // everyone done reading list before DMA overwrites buf0

    // wave-uniform store-instruction count per tile
    int wave_first = tid & ~63;
    int trips = 0;
    #pragma unroll
    for (int s = 0; s < RSL; ++s) if (wave_first + s * TPB < cnt) ++trips;

    // ---- 3) stage: exactly 5 glls per wave ----
    auto stage = [&](float* dst, int cin) {
        const char* gs = (const char*)(feat + (size_t)(b * CH + cin) * NPLANE);
        char* ls = (char*)dst;
        int wb = wid << 6;
        #pragma unroll
        for (int r = 0; r < 4; ++r)
            gll16(gs + (size_t)(r * TPB + tid) * 16, ls + (size_t)(r * TPB + wb) * 16);
        // tail slots 2048..2531: stride-60 wave overlap (dup slots get same data);
        // global clamped so pad slots hold finite junk (zero-weight taps only)
        int base4 = 2048 + wid * 60;
        int g4 = min(base4 + lane, 2499);
        gll16(gs + (size_t)g4 * 16, ls + (size_t)base4 * 16);
    };

    stage(buf0, cinbase + idx);
    __syncthreads();                       // drains vmcnt: tile0 resident

    // ---- 4) pipelined tile loop (double buffer) ----
    for (int k = 0; k < ntile; ++k) {
        if (k + 1 < ntile) stage((k & 1) ? buf0 : buf1, cinbase + idx + (k + 1) * 64);
        __builtin_amdgcn_sched_barrier(0);

        const float* __restrict__ bc = (k & 1) ? buf1 : buf0;
        int cin = cinbase + idx + k * 64;
        int pw  = cin % RS;
        int ph  = (cin / RS) % RS;

        #pragma unroll
        for (int s = 0; s < RSL; ++s) {
            if (pn[s] >= 0) {
                float sw = psw[s], sh = psh[s], bw = pbw[s], bh = pbh[s];
                float acc = 0.0f;
                #pragma unroll
                for (int iy = 0; iy < SR; ++iy) {
                    float y  = sh + ((float)ph + ((float)iy + 0.5f) * (1.0f / SR)) * bh;
                    bool  vy = (y >= -1.0f) && (y <= (float)HH);
                    float yy = fmaxf(y, 0.0f);
                    int   y0 = min((int)floorf(yy), HH - 1);
                    float yc = (y0 >= HH - 1) ? (float)y0 : yy;
                    float ly = yc - (float)y0;
                    float hy = 1.0f - ly;
                    #pragma unroll
                    for (int ix = 0; ix < SR; ++ix) {
                        float x  = sw + ((float)pw + ((float)ix + 0.5f) * (1.0f / SR)) * bw;
                        bool  vx = (x >= -1.0f) && (x <= (float)WW);
                        float xx = fmaxf(x, 0.0f);
                        int   x0 = min((int)floorf(xx), WW - 1);
                        float xc = (x0 >= WW - 1) ? (float)x0 : xx;
                        float lx = xc - (float)x0;
                        float hx = 1.0f - lx;
                        // clamp-by-weight: stray taps (pad/junk) carry weight 0
                        int o = y0 * WW + x0;
                        float v00 = bc[o],      v01 = bc[o + 1];
                        float v10 = bc[o + WW], v11 = bc[o + WW + 1];
                        float v = hy * (hx * v00 + lx * v01) + ly * (hx * v10 + lx * v11);
                        if (vy && vx) acc += v;
                    }
                }
                out[(size_t)pn[s] * CH + cin] = acc * (1.0f / (SR * SR));
            }
        }

        if (k + 1 < ntile) {
            waitv(trips);                  // stage(k+1) retired; own stores may linger
            __builtin_amdgcn_s_barrier();
            __builtin_amdgcn_sched_barrier(0);
        }
    }

    // ---- 5) pathological fallback (cnt > RSL*TPB): never hit for bench data ----
    if (cnt > RSL * TPB) {
        for (int t = 0; t < ntile; ++t) {
            int cin = cinbase + idx + t * 64;
            int pw = cin % RS, ph = (cin / RS) % RS;
            const float* base = feat + (size_t)(b * CH + cin) * NPLANE;
            int pos = 0;
            for (int k = 0; k < N; ++k) {
                if ((int)rois[(size_t)k * 5] == b) {
                    int r = pos - RSL * TPB;
                    if (r >= 0 && (r % TPB) == tid) {
                        const float* rp = rois + (size_t)k * 5;
                        float sw = rp[1] * SCALE - 0.5f;
                        float sh = rp[2] * SCALE - 0.5f;
                        float bw = (rp[3] * SCALE - 0.5f - sw) * (1.0f / RS);
                        float bh = (rp[4] * SCALE - 0.5f - sh) * (1.0f / RS);
                        out[(size_t)k * CH + cin] =
                            psroi_sample_f32(base, sw, sh, bw, bh, ph, pw);
                    }
                    ++pos;
                }
            }
        }
    }
}

// ---- general fallback (any B / N > MAXN): direct-gather per output ----
__global__ __launch_bounds__(256) void psroi_naive_kernel(
    const float* __restrict__ feat, const float* __restrict__ rois,
    float* __restrict__ out, int total)
{
    int o = blockIdx.x * blockDim.x + threadIdx.x;
    if (o >= total) return;
    int cin = o % CH;
    int n   = o / CH;
    int pw  = cin % RS;
    int ph  = (cin / RS) % RS;
    const float* r = rois + (size_t)n * 5;
    int bidx = (int)r[0];
    float sw = r[1] * SCALE - 0.5f;
    float sh = r[2] * SCALE - 0.5f;
    float bw = (r[3] * SCALE - 0.5f - sw) * (1.0f / RS);
    float bh = (r[4] * SCALE - 0.5f - sh) * (1.0f / RS);
    const float* base = feat + (size_t)(bidx * CH + cin) * NPLANE;
    out[o] = psroi_sample_f32(base, sw, sh, bw, bh, ph, pw);
}

extern "C" void kernel_launch(void* const* d_in, const int* in_sizes, int n_in,
                              void* d_out, int out_size, void* d_ws, size_t ws_size,
                              hipStream_t stream) {
    const float* feat = (const float*)d_in[0];
    const float* rois = (const float*)d_in[1];
    float* out = (float*)d_out;
    int N = in_sizes[1] / 5;
    int B = in_sizes[0] / (CH * NPLANE);

    if (N <= MAXN && B == 4) {
        psroi_pipe2_kernel<<<NBLK, TPB, 0, stream>>>(feat, rois, out, N);
    } else {
        int total = N * CH;
        psroi_naive_kernel<<<(total + 255) / 256, 256, 0, stream>>>(feat, rois, out, total);
    }
}